// Round 5
// baseline (1147.886 us; speedup 1.0000x reference)
//
#include <hip/hip_runtime.h>
#include <hip/hip_bf16.h>

// Problem constants (SymNetDP): B=64, S=4096, NGB=13, NG=48, DIM=3, NCH={8,8,1}
#define BATCH 64
#define SITES 4096
#define NGB 13
#define NGRP 48
#define SDIM 3

// ---------------------------------------------------------------------------
// Workspace layout (floats):
//   GW0 : (8,48,13)     =  4992   @ 0
//   GW1 : (8,48,104)    = 39936   @ 4992
//   GW2 : (48,104)      =  4992   @ 44928
//   Avc : (3,13)        =    39   @ 49920  (padded to 49984)
//   A0  : (B,8,S)       = 2097152 @ 49984
//   A1  : (B,8,S)       = 2097152 @ 2147136
//   A2  : (B,1,S)       =  262144 @ 4244288
//   PART: (64,16,3)     =  3072   @ 4506432
// ---------------------------------------------------------------------------
#define OFF_GW0 0
#define OFF_GW1 4992
#define OFF_GW2 44928
#define OFF_AVC 49920
#define OFF_A0  49984
#define OFF_A1  2147136
#define OFF_A2  4244288
#define OFF_PART 4506432

__device__ __forceinline__ float softplus_f(float h) {
    // stable: max(h,0) + log(1+exp(-|h|))
    return fmaxf(h, 0.f) + __logf(1.f + __expf(-fabsf(h)));
}

// ---------------------------------------------------------------------------
// Precompute: rotated weights GW0/GW1/GW2; Avc via per-(d,n,g) threads with
// atomicAdd (Avc zeroed by hipMemsetAsync before this kernel).
// ---------------------------------------------------------------------------
__global__ __launch_bounds__(256) void precompute_kernel(
    const float* __restrict__ Psi0, const float* __restrict__ Psi1,
    const float* __restrict__ Psi2, const float* __restrict__ wtVC,
    const float* __restrict__ gdiags, const int* __restrict__ perms,
    float* __restrict__ ws)
{
    float* GW0 = ws + OFF_GW0;
    float* GW1 = ws + OFF_GW1;
    float* GW2 = ws + OFF_GW2;
    float* Avc = ws + OFF_AVC;
    int t = blockIdx.x * 256 + threadIdx.x;
    if (t < 4992) {
        int j = t % NGB; int og = t / NGB; int g = og % NGRP; int o = og / NGRP;
        GW0[t] = Psi0[o * NGB + perms[g * NGB + j]];
    } else if (t < 44928) {
        int u = t - 4992;
        int k = u % 104; int og = u / 104; int g = og % NGRP; int o = og / NGRP;
        int c = k / NGB; int j = k % NGB;
        GW1[u] = Psi1[(o * 8 + c) * NGB + perms[g * NGB + j]];
    } else if (t < 49920) {
        int u = t - 44928;
        int k = u % 104; int g = u / 104; int c = k / NGB; int j = k % NGB;
        GW2[u] = Psi2[c * NGB + perms[g * NGB + j]];
    } else if (t < 49920 + 39 * NGRP) {
        int t2 = t - 49920;            // t2 = u*48 + g
        int g = t2 % NGRP, u = t2 / NGRP;
        int d = u / NGB, n = u % NGB;
        const int row = g * SDIM + d;
        float s = 0.f;
        for (int k = 0; k < NGRP * SDIM; k++) {
            int g2 = k / SDIM, d2 = k - g2 * SDIM;
            float p = wtVC[d2 * NGB + perms[g2 * NGB + n]];
            s = fmaf(gdiags[row * (NGRP * SDIM) + k], p, s);
        }
        atomicAdd(&Avc[u], s * (1.f / 48.f));
    }
}

// ---------------------------------------------------------------------------
// Register-tiled gconv layer with double-buffered weight chunks.
// Block: NCB output channels (OG = NCB*48 rows) x CT columns.
// Thread: TO rows x TC cols accumulators.
// K loop in 13-k chunks; chunk c+1 is prefetched to registers BEFORE chunk c's
// FMAs (global latency hidden), ds_written after, 1 barrier/chunk.
// Staging offsets (og=e/13 etc.) hoisted out of the c loop into registers.
// ---------------------------------------------------------------------------
template<int NCIN, int NCTOT, int NCB, int TO, int GOG, int TC, int GCOL, int CT>
__global__ __launch_bounds__(256) void layer_fused(
    const float* __restrict__ prev,   // (B, NCIN, S)
    const float* __restrict__ GW,     // (NCTOT*48, NCIN*13) row-major
    const float* __restrict__ bias,   // (NCTOT,)
    const int*   __restrict__ NN,     // (13, S)
    float* __restrict__ out)          // (B, NCTOT, S)
{
    constexpr int OG    = NCB * NGRP;          // rows per block
    constexpr int K     = NCIN * NGB;
    constexpr int WSTR  = OG + 4;              // padded LDS row stride
    constexpr int NBUF  = (NCIN > 1) ? 2 : 1;  // w double-buffer
    constexpr int CHUNK = OG * NGB;            // elems per 13-k w chunk
    constexpr int NPRE  = (CHUNK + 255) / 256;
    constexpr bool FULL = (CHUNK % 256) == 0;
    constexpr int PSTR  = CT + 1;
    constexpr int GPO   = NGRP / TO;           // thread-groups per o
    constexpr int OSPL  = NCTOT / NCB;

    static_assert(GOG * GCOL == 256, "");
    static_assert(TO * GOG == OG, "");
    static_assert(TC * GCOL == CT, "");
    static_assert(NGRP % TO == 0, "");
    static_assert(GOG * PSTR <= NBUF * NGB * WSTR, "partials fit in w_lds");

    __shared__ int   nn_lds[NGB * CT];
    __shared__ float x_lds[K * CT];                // [k][col]
    __shared__ float w_lds[NBUF * NGB * WSTR];     // [buf][j][og]

    const int tid = threadIdx.x;
    const int og_group  = tid % GOG;
    const int col_group = tid / GOG;
    const int og0  = og_group * TO;
    const int col0 = col_group * TC;

    const int oblk = blockIdx.x % OSPL;
    const int bs   = blockIdx.x / OSPL;
    const int b    = bs / (SITES / CT);
    const int s0   = (bs % (SITES / CT)) * CT;

    const float* GWb = GW + (size_t)(oblk * OG) * K;

    // --- hoisted staging decomposition (invariant over c) -------------------
    int goff[NPRE];   // GW element offset: og*K + j
    int wadr[NPRE];   // LDS float index:  j*WSTR + og
#pragma unroll
    for (int i = 0; i < NPRE; i++) {
        int e = tid + i * 256;
        int og = e / NGB, j = e - og * NGB;
        goff[i] = og * K + j;
        wadr[i] = j * WSTR + og;
    }

    // --- preload w chunk 0 into registers (latency hidden by staging) -------
    float wpre[NPRE];
#pragma unroll
    for (int i = 0; i < NPRE; i++)
        if (FULL || tid + i * 256 < CHUNK) wpre[i] = GWb[goff[i]];

    // --- stage nn tile ------------------------------------------------------
    for (int e = tid; e < NGB * CT; e += 256) {
        int j = e / CT, col = e - j * CT;
        nn_lds[e] = NN[j * SITES + s0 + col];
    }
    __syncthreads();
    // --- stage gathered x tile, transposed [k][col] -------------------------
    for (int e = tid; e < K * CT; e += 256) {
        int k = e / CT, col = e - k * CT;
        int c = k / NGB, j = k - c * NGB;
        x_lds[e] = prev[((size_t)b * NCIN + c) * SITES + nn_lds[j * CT + col]];
    }
    // --- write w chunk 0 ----------------------------------------------------
#pragma unroll
    for (int i = 0; i < NPRE; i++)
        if (FULL || tid + i * 256 < CHUNK) w_lds[wadr[i]] = wpre[i];
    __syncthreads();

    const int o_local = og0 / NGRP;
    const float bo = bias[oblk * NCB + o_local];
    float h[TO][TC];
#pragma unroll
    for (int i = 0; i < TO; i++)
#pragma unroll
        for (int q = 0; q < TC; q++) h[i][q] = bo;

    // --- K loop, 13-k chunks, double-buffered -------------------------------
#pragma unroll 1
    for (int c = 0; c < NCIN; c++) {
        if (c + 1 < NCIN) {         // prefetch next chunk (no wait here)
#pragma unroll
            for (int i = 0; i < NPRE; i++)
                if (FULL || tid + i * 256 < CHUNK)
                    wpre[i] = GWb[goff[i] + (c + 1) * NGB];
        }
        const float* wb = &w_lds[(c & (NBUF - 1)) * NGB * WSTR];
        const float* xc = &x_lds[c * NGB * CT];
#pragma unroll
        for (int j = 0; j < NGB; j++) {
            float wv[TO], xv[TC];
#pragma unroll
            for (int i = 0; i < TO; i++) wv[i] = wb[j * WSTR + og0 + i];
#pragma unroll
            for (int q = 0; q < TC; q++) xv[q] = xc[j * CT + col0 + q];
#pragma unroll
            for (int i = 0; i < TO; i++)
#pragma unroll
                for (int q = 0; q < TC; q++)
                    h[i][q] = fmaf(wv[i], xv[q], h[i][q]);
        }
        if (c + 1 < NCIN) {         // commit prefetched chunk
            float* wn = &w_lds[((c + 1) & (NBUF - 1)) * NGB * WSTR];
#pragma unroll
            for (int i = 0; i < NPRE; i++)
                if (FULL || tid + i * 256 < CHUNK) wn[wadr[i]] = wpre[i];
        }
        __syncthreads();
    }

    // --- epilogue: softplus, partial row-sum, group-mean --------------------
    float sp[TC];
#pragma unroll
    for (int q = 0; q < TC; q++) {
        float s = 0.f;
#pragma unroll
        for (int i = 0; i < TO; i++) s += softplus_f(h[i][q]);
        sp[q] = s;
    }
    float* part = w_lds;                    // reuse (barrier above protects)
#pragma unroll
    for (int q = 0; q < TC; q++) part[og_group * PSTR + col0 + q] = sp[q];
    __syncthreads();
    for (int e = tid; e < NCB * CT; e += 256) {
        int oo = e / CT, col = e - oo * CT;
        float s = 0.f;
#pragma unroll
        for (int r = 0; r < GPO; r++) s += part[(oo * GPO + r) * PSTR + col];
        out[((size_t)b * NCTOT + oblk * NCB + oo) * SITES + s0 + col] =
            s * (1.f / 48.f);
    }
}

// ---------------------------------------------------------------------------
// Reduce stage A: per (b, s-chunk) block -> 3 partial sums
// ---------------------------------------------------------------------------
__global__ __launch_bounds__(256) void reduce_a(
    const float* __restrict__ A2,     // (B, S)
    const int*   __restrict__ NN,     // (13, S)
    const int*   __restrict__ s2sh,   // (S,)
    const float* __restrict__ sw,     // (NSHELLS,)
    const float* __restrict__ Avc,    // (3, 13)
    float* __restrict__ partial)      // (B, 16, 3)
{
    const int b = blockIdx.x >> 4;
    const int chunk = blockIdx.x & 15;
    const int tid = threadIdx.x;
    const int s = (chunk << 8) + tid;
    const float* a = A2 + (size_t)b * SITES;

    float y0 = 0.f, y1 = 0.f, y2 = 0.f;
#pragma unroll
    for (int n = 0; n < NGB; n++) {
        float v = a[NN[n * SITES + s]];
        y0 = fmaf(Avc[n],           v, y0);
        y1 = fmaf(Avc[NGB + n],     v, y1);
        y2 = fmaf(Avc[2 * NGB + n], v, y2);
    }
    const float wgt = sw[s2sh[s]];
    y0 *= wgt; y1 *= wgt; y2 *= wgt;

    __shared__ float red[3][256];
    red[0][tid] = y0; red[1][tid] = y1; red[2][tid] = y2;
    __syncthreads();
    for (int st = 128; st > 0; st >>= 1) {
        if (tid < st) {
            red[0][tid] += red[0][tid + st];
            red[1][tid] += red[1][tid + st];
            red[2][tid] += red[2][tid + st];
        }
        __syncthreads();
    }
    if (tid < 3) partial[(b * 16 + chunk) * 3 + tid] = red[tid][0];
}

__global__ __launch_bounds__(256) void reduce_b(
    const float* __restrict__ partial, float* __restrict__ out)
{
    int t = threadIdx.x;
    if (t < BATCH * 3) {
        int b = t / 3, d = t - b * 3;
        float s = 0.f;
        for (int c = 0; c < 16; c++) s += partial[(b * 16 + c) * 3 + d];
        out[t] = s * (1.f / (float)SITES);
    }
}

// ---------------------------------------------------------------------------
extern "C" void kernel_launch(void* const* d_in, const int* in_sizes, int n_in,
                              void* d_out, int out_size, void* d_ws, size_t ws_size,
                              hipStream_t stream)
{
    const float* InStates = (const float*)d_in[0];   // (64,1,4096)
    const float* Psi0     = (const float*)d_in[1];   // (8,1,13)
    const float* bias0    = (const float*)d_in[2];   // (8,1)
    const float* Psi1     = (const float*)d_in[3];   // (8,8,13)
    const float* bias1    = (const float*)d_in[4];   // (8,1)
    const float* Psi2     = (const float*)d_in[5];   // (1,8,13)
    const float* bias2    = (const float*)d_in[6];   // (1,1)
    const float* wtVC     = (const float*)d_in[7];   // (3,13)
    const float* ShellW   = (const float*)d_in[8];   // (8,)
    const float* gdiags   = (const float*)d_in[9];   // (144,144)
    const int*   GnnPerms = (const int*)d_in[10];    // (48,13)
    const int*   NNSites  = (const int*)d_in[11];    // (13,4096)
    const int*   S2Sh     = (const int*)d_in[12];    // (4096,)

    float* ws   = (float*)d_ws;
    float* GW0  = ws + OFF_GW0;
    float* GW1  = ws + OFF_GW1;
    float* GW2  = ws + OFF_GW2;
    float* Avc  = ws + OFF_AVC;
    float* A0   = ws + OFF_A0;
    float* A1   = ws + OFF_A1;
    float* A2   = ws + OFF_A2;
    float* PART = ws + OFF_PART;

    float* out = (float*)d_out;  // (64,3) f32

    hipMemsetAsync(Avc, 0, 39 * sizeof(float), stream);
    precompute_kernel<<<203, 256, 0, stream>>>(Psi0, Psi1, Psi2, wtVC, gdiags,
                                               GnnPerms, ws);

    // L0: NCIN=1, NCB=4 (2 o-blocks); CT=64, tile 6x8 = 48 accs; LDS ~17 KB
    layer_fused<1, 8, 4, 6, 32, 8, 8, 64>
        <<<BATCH * (SITES / 64) * 2, 256, 0, stream>>>(InStates, GW0, bias0, NNSites, A0);
    // L1: NCIN=8, NCB=4 (2 o-blocks); CT=64, tile 6x8 = 48 accs; LDS ~50 KB
    layer_fused<8, 8, 4, 6, 32, 8, 8, 64>
        <<<BATCH * (SITES / 64) * 2, 256, 0, stream>>>(A0, GW1, bias1, NNSites, A1);
    // L2: NCIN=8, NCB=1; CT=64, tile 3x4 = 12 accs; LDS ~35 KB
    layer_fused<8, 1, 1, 3, 16, 4, 16, 64>
        <<<BATCH * (SITES / 64), 256, 0, stream>>>(A1, GW2, bias2, NNSites, A2);

    reduce_a<<<BATCH * 16, 256, 0, stream>>>(A2, NNSites, S2Sh, ShellW, Avc, PART);
    reduce_b<<<1, 256, 0, stream>>>(PART, out);
}

// Round 6
// 606.655 us; speedup vs baseline: 1.8922x; 1.8922x over previous
//
#include <hip/hip_runtime.h>
#include <hip/hip_bf16.h>

// Problem constants (SymNetDP): B=64, S=4096, NGB=13, NG=48, DIM=3, NCH={8,8,1}
#define BATCH 64
#define SITES 4096
#define NGB 13
#define NGRP 48
#define SDIM 3

// ---------------------------------------------------------------------------
// Workspace layout (floats):
//   GW0T: [2][13][192]        =  4992   @ 0        (transposed chunks)
//   GW1T: [2][8][13][192]     = 39936   @ 4992
//   GW2T: [8][13][48]         =  4992   @ 44928
//   Avc : (3,13)              =    39   @ 49920  (padded to 49984)
//   A0  : (B,8,S)             = 2097152 @ 49984
//   A1  : (B,8,S)             = 2097152 @ 2147136
//   A2  : (B,1,S)             =  262144 @ 4244288
//   PART: (64,16,3)           =  3072   @ 4506432
// ---------------------------------------------------------------------------
#define OFF_GW0 0
#define OFF_GW1 4992
#define OFF_GW2 44928
#define OFF_AVC 49920
#define OFF_A0  49984
#define OFF_A1  2147136
#define OFF_A2  4244288
#define OFF_PART 4506432

__device__ __forceinline__ float softplus_f(float h) {
    // stable: max(h,0) + log(1+exp(-|h|))
    return fmaxf(h, 0.f) + __logf(1.f + __expf(-fabsf(h)));
}

// ---------------------------------------------------------------------------
// Precompute rotated weights directly in the per-block LDS staging layout:
//   GW0T[oblk*2496 + j*192 + og]  (og = local row, o = oblk*4 + og/48, g=og%48)
//   GW1T[oblk*19968 + c*2496 + j*192 + og]
//   GW2T[c*624 + j*48 + g]
// plus Avc[d,n] = (1/48) sum_g (gdiags @ P)[g*3+d, n] via atomics.
// ---------------------------------------------------------------------------
__global__ __launch_bounds__(256) void precompute_kernel(
    const float* __restrict__ Psi0, const float* __restrict__ Psi1,
    const float* __restrict__ Psi2, const float* __restrict__ wtVC,
    const float* __restrict__ gdiags, const int* __restrict__ perms,
    float* __restrict__ ws)
{
    float* GW0T = ws + OFF_GW0;
    float* GW1T = ws + OFF_GW1;
    float* GW2T = ws + OFF_GW2;
    float* Avc  = ws + OFF_AVC;
    int t = blockIdx.x * 256 + threadIdx.x;
    if (t < 4992) {
        // u = oblk*2496 + j*192 + og
        int og = t % 192; int v = t / 192; int j = v % NGB; int oblk = v / NGB;
        int o = oblk * 4 + og / NGRP, g = og % NGRP;
        GW0T[t] = Psi0[o * NGB + perms[g * NGB + j]];
    } else if (t < 44928) {
        int u = t - 4992;      // u = oblk*19968 + c*2496 + j*192 + og
        int og = u % 192; int v = u / 192; int j = v % NGB; int w = v / NGB;
        int c = w % 8; int oblk = w / 8;
        int o = oblk * 4 + og / NGRP, g = og % NGRP;
        GW1T[u] = Psi1[(o * 8 + c) * NGB + perms[g * NGB + j]];
    } else if (t < 49920) {
        int u = t - 44928;     // u = c*624 + j*48 + g
        int g = u % NGRP; int v = u / NGRP; int j = v % NGB; int c = v / NGB;
        GW2T[u] = Psi2[c * NGB + perms[g * NGB + j]];
    } else if (t < 49920 + 39 * NGRP) {
        int t2 = t - 49920;            // t2 = u*48 + g
        int g = t2 % NGRP, u = t2 / NGRP;
        int d = u / NGB, n = u % NGB;
        const int row = g * SDIM + d;
        float s = 0.f;
        for (int k = 0; k < NGRP * SDIM; k++) {
            int g2 = k / SDIM, d2 = k - g2 * SDIM;
            float p = wtVC[d2 * NGB + perms[g2 * NGB + n]];
            s = fmaf(gdiags[row * (NGRP * SDIM) + k], p, s);
        }
        atomicAdd(&Avc[u], s * (1.f / 48.f));
    }
}

// ---------------------------------------------------------------------------
// Register-tiled gconv layer, v6.
// Weights arrive pre-transposed -> per-chunk staging is a LINEAR copy
// (no index math, coalesced). Double-buffered in LDS with a small register
// prefetch wp[NLD] (NLD<=10 VGPRs, no address arrays -> no round-5 blowup).
// One barrier per chunk. Math order identical to rounds 1-4 (absmax 0).
// ---------------------------------------------------------------------------
template<int NCIN, int NCTOT, int NCB, int TO, int GOG, int TC, int GCOL, int CT>
__global__ __launch_bounds__(256) void layer_v6(
    const float* __restrict__ prev,   // (B, NCIN, S)
    const float* __restrict__ GWT,    // [OSPL][NCIN][13][OG] transposed
    const float* __restrict__ bias,   // (NCTOT,)
    const int*   __restrict__ NN,     // (13, S)
    float* __restrict__ out)          // (B, NCTOT, S)
{
    constexpr int OG    = NCB * NGRP;          // rows per block
    constexpr int K     = NCIN * NGB;
    constexpr int CHUNK = OG * NGB;            // floats per 13-k chunk
    constexpr int NBUF  = (NCIN > 1) ? 2 : 1;
    constexpr int NLD   = (CHUNK + 255) / 256; // prefetch regs per thread
    constexpr int PSTR  = CT + 1;
    constexpr int GPO   = NGRP / TO;
    constexpr int OSPL  = NCTOT / NCB;

    static_assert(GOG * GCOL == 256, "");
    static_assert(TO * GOG == OG, "");
    static_assert(TC * GCOL == CT, "");
    static_assert(NGRP % TO == 0, "");
    static_assert(GOG * PSTR <= NBUF * CHUNK, "partials fit in w_lds");

    __shared__ int   nn_lds[NGB * CT];
    __shared__ float x_lds[K * CT];            // [k][col]
    __shared__ float w_lds[NBUF * CHUNK];      // [buf][j][og], linear

    const int tid = threadIdx.x;
    const int og_group  = tid % GOG;
    const int col_group = tid / GOG;
    const int og0  = og_group * TO;
    const int col0 = col_group * TC;

    const int oblk = blockIdx.x % OSPL;
    const int bs   = blockIdx.x / OSPL;
    const int b    = bs / (SITES / CT);
    const int s0   = (bs % (SITES / CT)) * CT;

    const float* GWb = GWT + (size_t)oblk * (NCIN * CHUNK);

    // --- stage nn tile ------------------------------------------------------
    for (int e = tid; e < NGB * CT; e += 256) {
        int j = e / CT, col = e % CT;          // CT is pow2 -> shifts
        nn_lds[e] = NN[j * SITES + s0 + col];
    }
    __syncthreads();

    // --- preload w chunk 0 (linear, coalesced; latency covered by x gather) -
    float wp[NLD];
#pragma unroll
    for (int i = 0; i < NLD; i++) {
        int e = tid + i * 256;
        if (e < CHUNK) wp[i] = GWb[e];
    }

    // --- stage gathered x tile, transposed [k][col] -------------------------
    const float* pb = prev + (size_t)b * NCIN * SITES;
    for (int e = tid; e < K * CT; e += 256) {
        int k = e / CT, col = e % CT;
        int c = k / NGB, j = k - c * NGB;
        x_lds[e] = pb[c * SITES + nn_lds[j * CT + col]];
    }
    // --- commit chunk 0 -----------------------------------------------------
#pragma unroll
    for (int i = 0; i < NLD; i++) {
        int e = tid + i * 256;
        if (e < CHUNK) w_lds[e] = wp[i];
    }
    __syncthreads();

    const float bo = bias[oblk * NCB + og0 / NGRP];
    float h[TO][TC];
#pragma unroll
    for (int i = 0; i < TO; i++)
#pragma unroll
        for (int q = 0; q < TC; q++) h[i][q] = bo;

    // --- K loop, 13-k chunks, LDS double-buffer, 1 barrier/chunk ------------
#pragma unroll 1
    for (int c = 0; c < NCIN; c++) {
        if (c + 1 < NCIN) {                   // prefetch next chunk (linear)
            const float* src = GWb + (c + 1) * CHUNK;
#pragma unroll
            for (int i = 0; i < NLD; i++) {
                int e = tid + i * 256;
                if (e < CHUNK) wp[i] = src[e];
            }
        }
        const float* wb = w_lds + (c & (NBUF - 1)) * CHUNK;
        const float* xc = x_lds + c * NGB * CT;
#pragma unroll
        for (int j = 0; j < NGB; j++) {
            float wv[TO], xv[TC];
#pragma unroll
            for (int i = 0; i < TO; i++) wv[i] = wb[j * OG + og0 + i];
#pragma unroll
            for (int q = 0; q < TC; q++) xv[q] = xc[j * CT + col0 + q];
#pragma unroll
            for (int i = 0; i < TO; i++)
#pragma unroll
                for (int q = 0; q < TC; q++)
                    h[i][q] = fmaf(wv[i], xv[q], h[i][q]);
        }
        if (c + 1 < NCIN) {                   // commit prefetched chunk
            float* wn = w_lds + ((c + 1) & (NBUF - 1)) * CHUNK;
#pragma unroll
            for (int i = 0; i < NLD; i++) {
                int e = tid + i * 256;
                if (e < CHUNK) wn[e] = wp[i];
            }
        }
        __syncthreads();
    }

    // --- epilogue: softplus, partial row-sum, group-mean --------------------
    float sp[TC];
#pragma unroll
    for (int q = 0; q < TC; q++) {
        float s = 0.f;
#pragma unroll
        for (int i = 0; i < TO; i++) s += softplus_f(h[i][q]);
        sp[q] = s;
    }
    float* part = w_lds;                       // reuse (barrier above protects)
#pragma unroll
    for (int q = 0; q < TC; q++) part[og_group * PSTR + col0 + q] = sp[q];
    __syncthreads();
    for (int e = tid; e < NCB * CT; e += 256) {
        int oo = e / CT, col = e % CT;
        float s = 0.f;
#pragma unroll
        for (int r = 0; r < GPO; r++) s += part[(oo * GPO + r) * PSTR + col];
        out[((size_t)b * NCTOT + oblk * NCB + oo) * SITES + s0 + col] =
            s * (1.f / 48.f);
    }
}

// ---------------------------------------------------------------------------
// Reduce stage A: per (b, s-chunk) block -> 3 partial sums
// ---------------------------------------------------------------------------
__global__ __launch_bounds__(256) void reduce_a(
    const float* __restrict__ A2,     // (B, S)
    const int*   __restrict__ NN,     // (13, S)
    const int*   __restrict__ s2sh,   // (S,)
    const float* __restrict__ sw,     // (NSHELLS,)
    const float* __restrict__ Avc,    // (3, 13)
    float* __restrict__ partial)      // (B, 16, 3)
{
    const int b = blockIdx.x >> 4;
    const int chunk = blockIdx.x & 15;
    const int tid = threadIdx.x;
    const int s = (chunk << 8) + tid;
    const float* a = A2 + (size_t)b * SITES;

    float y0 = 0.f, y1 = 0.f, y2 = 0.f;
#pragma unroll
    for (int n = 0; n < NGB; n++) {
        float v = a[NN[n * SITES + s]];
        y0 = fmaf(Avc[n],           v, y0);
        y1 = fmaf(Avc[NGB + n],     v, y1);
        y2 = fmaf(Avc[2 * NGB + n], v, y2);
    }
    const float wgt = sw[s2sh[s]];
    y0 *= wgt; y1 *= wgt; y2 *= wgt;

    __shared__ float red[3][256];
    red[0][tid] = y0; red[1][tid] = y1; red[2][tid] = y2;
    __syncthreads();
    for (int st = 128; st > 0; st >>= 1) {
        if (tid < st) {
            red[0][tid] += red[0][tid + st];
            red[1][tid] += red[1][tid + st];
            red[2][tid] += red[2][tid + st];
        }
        __syncthreads();
    }
    if (tid < 3) partial[(b * 16 + chunk) * 3 + tid] = red[tid][0];
}

__global__ __launch_bounds__(256) void reduce_b(
    const float* __restrict__ partial, float* __restrict__ out)
{
    int t = threadIdx.x;
    if (t < BATCH * 3) {
        int b = t / 3, d = t - b * 3;
        float s = 0.f;
        for (int c = 0; c < 16; c++) s += partial[(b * 16 + c) * 3 + d];
        out[t] = s * (1.f / (float)SITES);
    }
}

// ---------------------------------------------------------------------------
extern "C" void kernel_launch(void* const* d_in, const int* in_sizes, int n_in,
                              void* d_out, int out_size, void* d_ws, size_t ws_size,
                              hipStream_t stream)
{
    const float* InStates = (const float*)d_in[0];   // (64,1,4096)
    const float* Psi0     = (const float*)d_in[1];   // (8,1,13)
    const float* bias0    = (const float*)d_in[2];   // (8,1)
    const float* Psi1     = (const float*)d_in[3];   // (8,8,13)
    const float* bias1    = (const float*)d_in[4];   // (8,1)
    const float* Psi2     = (const float*)d_in[5];   // (1,8,13)
    const float* bias2    = (const float*)d_in[6];   // (1,1)
    const float* wtVC     = (const float*)d_in[7];   // (3,13)
    const float* ShellW   = (const float*)d_in[8];   // (8,)
    const float* gdiags   = (const float*)d_in[9];   // (144,144)
    const int*   GnnPerms = (const int*)d_in[10];    // (48,13)
    const int*   NNSites  = (const int*)d_in[11];    // (13,4096)
    const int*   S2Sh     = (const int*)d_in[12];    // (4096,)

    float* ws   = (float*)d_ws;
    float* GW0T = ws + OFF_GW0;
    float* GW1T = ws + OFF_GW1;
    float* GW2T = ws + OFF_GW2;
    float* Avc  = ws + OFF_AVC;
    float* A0   = ws + OFF_A0;
    float* A1   = ws + OFF_A1;
    float* A2   = ws + OFF_A2;
    float* PART = ws + OFF_PART;

    float* out = (float*)d_out;  // (64,3) f32

    hipMemsetAsync(Avc, 0, 39 * sizeof(float), stream);
    precompute_kernel<<<203, 256, 0, stream>>>(Psi0, Psi1, Psi2, wtVC, gdiags,
                                               GnnPerms, ws);

    // L0: NCIN=1, NCB=4 (2 o-blocks); CT=64, tile 6x8 = 48 accs
    layer_v6<1, 8, 4, 6, 32, 8, 8, 64>
        <<<BATCH * (SITES / 64) * 2, 256, 0, stream>>>(InStates, GW0T, bias0, NNSites, A0);
    // L1: NCIN=8, NCB=4 (2 o-blocks); CT=64, tile 6x8 = 48 accs; LDS ~50 KB
    layer_v6<8, 8, 4, 6, 32, 8, 8, 64>
        <<<BATCH * (SITES / 64) * 2, 256, 0, stream>>>(A0, GW1T, bias1, NNSites, A1);
    // L2: NCIN=8, NCB=1; CT=64, tile 3x4 = 12 accs
    layer_v6<8, 1, 1, 3, 16, 4, 16, 64>
        <<<BATCH * (SITES / 64), 256, 0, stream>>>(A1, GW2T, bias2, NNSites, A2);

    reduce_a<<<BATCH * 16, 256, 0, stream>>>(A2, NNSites, S2Sh, ShellW, Avc, PART);
    reduce_b<<<1, 256, 0, stream>>>(PART, out);
}

// Round 7
// 604.205 us; speedup vs baseline: 1.8998x; 1.0041x over previous
//
#include <hip/hip_runtime.h>
#include <hip/hip_bf16.h>

// Problem constants (SymNetDP): B=64, S=4096, NGB=13, NG=48, DIM=3, NCH={8,8,1}
#define BATCH 64
#define SITES 4096
#define NGB 13
#define NGRP 48
#define SDIM 3

typedef __bf16 bf16x8 __attribute__((ext_vector_type(8)));
typedef float  f32x4  __attribute__((ext_vector_type(4)));

// ---------------------------------------------------------------------------
// Workspace layout:
//   Avc  : 39 f32 (pad 64)                      @ float 0
//   U    : bf16 region, 135168 elems            @ float 64
//     W0H [2*192][32] 12288 | W0L +12288 | W1H [2*192][128] @24576 49152 |
//     W1L @73728 | W2H [48][128] @122880 6144 | W2L @129024
//   A0   : (B,8,S) 2097152                      @ float 67648   (A2 aliases)
//   A1   : (B,8,S) 2097152                      @ float 2164800
//   PART : (64,16,3) 3072                       @ float 4261952
//   total 4265024 floats (< round-6's 4509504 -> fits same ws)
// ---------------------------------------------------------------------------
#define OFF_AVC  0
#define OFF_U    64
#define OFF_A0   67648
#define OFF_A1   2164800
#define OFF_PART 4261952
#define UW0H 0
#define UW0L 12288
#define UW1H 24576
#define UW1L 73728
#define UW2H 122880
#define UW2L 129024

__device__ __forceinline__ float softplus_f(float h) {
    return fmaxf(h, 0.f) + __logf(1.f + __expf(-fabsf(h)));
}

// ---------------------------------------------------------------------------
// Precompute: rotated weights, bf16 hi/lo split, in MFMA A-operand-friendly
// [row][KPAD] row-major layout (zero-padded K). Rows = oblk*192 + o_loc*48+g.
// Plus Avc (atomics, zeroed by memset).
// ---------------------------------------------------------------------------
__global__ __launch_bounds__(256) void precompute_kernel(
    const float* __restrict__ Psi0, const float* __restrict__ Psi1,
    const float* __restrict__ Psi2, const float* __restrict__ wtVC,
    const float* __restrict__ gdiags, const int* __restrict__ perms,
    float* __restrict__ ws)
{
    float*  Avc = ws + OFF_AVC;
    __bf16* U   = (__bf16*)(ws + OFF_U);
    int t = blockIdx.x * 256 + threadIdx.x;
    if (t < 12288) {                       // W0: [2*192][32]
        int k = t & 31, row = t >> 5;
        int og = row % 192, oblk = row / 192;
        int o = oblk * 4 + og / NGRP, g = og % NGRP;
        float w = (k < NGB) ? Psi0[o * NGB + perms[g * NGB + k]] : 0.f;
        __bf16 hi = (__bf16)w;
        U[UW0H + t] = hi;
        U[UW0L + t] = (__bf16)(w - (float)hi);
    } else if (t < 61440) {                // W1: [2*192][128]
        int u = t - 12288;
        int k = u & 127, row = u >> 7;
        int og = row % 192, oblk = row / 192;
        int o = oblk * 4 + og / NGRP, g = og % NGRP;
        float w = 0.f;
        if (k < 104) { int c = k / NGB, j = k - c * NGB;
                       w = Psi1[(o * 8 + c) * NGB + perms[g * NGB + j]]; }
        __bf16 hi = (__bf16)w;
        U[UW1H + u] = hi;
        U[UW1L + u] = (__bf16)(w - (float)hi);
    } else if (t < 67584) {                // W2: [48][128]
        int u = t - 61440;
        int k = u & 127, g = u >> 7;
        float w = 0.f;
        if (k < 104) { int c = k / NGB, j = k - c * NGB;
                       w = Psi2[c * NGB + perms[g * NGB + j]]; }
        __bf16 hi = (__bf16)w;
        U[UW2H + u] = hi;
        U[UW2L + u] = (__bf16)(w - (float)hi);
    } else if (t < 67584 + 39 * NGRP) {    // Avc
        int t2 = t - 67584;
        int g = t2 % NGRP, u = t2 / NGRP;
        int d = u / NGB, n = u % NGB;
        const int row = g * SDIM + d;
        float s = 0.f;
        for (int k = 0; k < NGRP * SDIM; k++) {
            int g2 = k / SDIM, d2 = k - g2 * SDIM;
            float p = wtVC[d2 * NGB + perms[g2 * NGB + n]];
            s = fmaf(gdiags[row * (NGRP * SDIM) + k], p, s);
        }
        atomicAdd(&Avc[u], s * (1.f / 48.f));
    }
}

// ---------------------------------------------------------------------------
// MFMA gconv layer (bf16x3 split emulating f32).
// GEMM per block: H[M=NCB*48][CT cols], K pad -> KPAD. 4 waves; each wave
// owns exactly one output channel (MT_W*16 == 48 rows) x NT_W*16 cols.
// W hi/lo: global, per-lane dwordx4 (A-frag: A[m=lane&15][k=quad*8+j]).
// X hi/lo: LDS [col][KSTR] (B-frag: B[k=quad*8+j][n=lane&15]).
// D: row=quad*4+r, col=lane&15 (verified layouts, learn_hip m89/m120).
// Epilogue: softplus(acc+bias), quad-shuffle reduce over 48 g-rows, *1/48.
// ---------------------------------------------------------------------------
template<int NCIN, int NCTOT, int NCB, int CT, int KPAD, int NWN>
__global__ __launch_bounds__(256) void layer_mfma(
    const float* __restrict__ prev,   // (B, NCIN, S)
    const __bf16* __restrict__ Wh,    // [OSPL*M][KPAD]
    const __bf16* __restrict__ Wl,
    const float* __restrict__ bias,   // (NCTOT,)
    const int*   __restrict__ NN,     // (13, S)
    float* __restrict__ out)          // (B, NCTOT, S)
{
    constexpr int K      = NCIN * NGB;
    constexpr int M      = NCB * NGRP;
    constexpr int MTILES = M / 16, NTILES = CT / 16;
    constexpr int NWM    = 4 / NWN;
    constexpr int MT_W   = MTILES / NWM, NT_W = NTILES / NWN;
    constexpr int KT     = KPAD / 32;
    constexpr int KSTR   = KPAD + 8;       // +8 bf16 -> 2-way-only LDS banks
    constexpr int OSPL   = NCTOT / NCB;

    static_assert(MT_W * 16 == NGRP, "wave must cover exactly one o");
    static_assert(NWM * MT_W == MTILES && NWN * NT_W == NTILES, "");
    static_assert((KPAD & 31) == 0, "");

    __shared__ int    nn_lds[NGB * CT];
    __shared__ __bf16 xh_lds[CT * KSTR];
    __shared__ __bf16 xl_lds[CT * KSTR];

    const int tid  = threadIdx.x;
    const int wave = tid >> 6, lane = tid & 63;
    const int m16  = lane & 15, quad = lane >> 4;

    const int oblk = blockIdx.x % OSPL;
    const int bs   = blockIdx.x / OSPL;
    const int b    = bs / (SITES / CT);
    const int s0   = (bs % (SITES / CT)) * CT;

    // --- stage nn tile ------------------------------------------------------
    for (int e = tid; e < NGB * CT; e += 256) {
        int j = e / CT, col = e % CT;
        nn_lds[e] = NN[j * SITES + s0 + col];
    }
    __syncthreads();

    // --- gather + bf16-split X into LDS [col][k] (zero-padded K..KPAD) ------
    const float* pb = prev + (size_t)b * NCIN * SITES;
    for (int e = tid; e < CT * KPAD; e += 256) {
        int col = e / KPAD, k = e % KPAD;       // KPAD pow2 -> shifts
        float v = 0.f;
        if (k < K) {
            int c = k / NGB, j = k - c * NGB;
            v = pb[c * SITES + nn_lds[j * CT + col]];
        }
        __bf16 hi = (__bf16)v;
        xh_lds[col * KSTR + k] = hi;
        xl_lds[col * KSTR + k] = (__bf16)(v - (float)hi);
    }
    __syncthreads();

    const int wave_mt0 = (wave / NWN) * MT_W;
    const int wave_nt0 = (wave % NWN) * NT_W;
    const int o_g      = oblk * NCB + (wave_mt0 * 16) / NGRP;

    const __bf16* WhB = Wh + (size_t)(oblk * M) * KPAD;
    const __bf16* WlB = Wl + (size_t)(oblk * M) * KPAD;

    f32x4 acc[MT_W][NT_W];
#pragma unroll
    for (int mt = 0; mt < MT_W; mt++)
#pragma unroll
        for (int nt = 0; nt < NT_W; nt++) acc[mt][nt] = (f32x4){0.f, 0.f, 0.f, 0.f};

    // --- K loop: 3 MFMAs per tile per K32 step (hi*hi + lo*hi + hi*lo) ------
#pragma unroll
    for (int kt = 0; kt < KT; kt++) {
        const int koff = kt * 32 + quad * 8;
        bf16x8 ah[MT_W], al[MT_W], bh[NT_W], bl[NT_W];
#pragma unroll
        for (int mt = 0; mt < MT_W; mt++) {
            int row = (wave_mt0 + mt) * 16 + m16;
            ah[mt] = *(const bf16x8*)(WhB + (size_t)row * KPAD + koff);
            al[mt] = *(const bf16x8*)(WlB + (size_t)row * KPAD + koff);
        }
#pragma unroll
        for (int nt = 0; nt < NT_W; nt++) {
            int col = (wave_nt0 + nt) * 16 + m16;
            bh[nt] = *(const bf16x8*)(&xh_lds[col * KSTR + koff]);
            bl[nt] = *(const bf16x8*)(&xl_lds[col * KSTR + koff]);
        }
#pragma unroll
        for (int mt = 0; mt < MT_W; mt++)
#pragma unroll
            for (int nt = 0; nt < NT_W; nt++) {
                acc[mt][nt] = __builtin_amdgcn_mfma_f32_16x16x32_bf16(
                    ah[mt], bh[nt], acc[mt][nt], 0, 0, 0);
                acc[mt][nt] = __builtin_amdgcn_mfma_f32_16x16x32_bf16(
                    al[mt], bh[nt], acc[mt][nt], 0, 0, 0);
                acc[mt][nt] = __builtin_amdgcn_mfma_f32_16x16x32_bf16(
                    ah[mt], bl[nt], acc[mt][nt], 0, 0, 0);
            }
    }

    // --- epilogue: softplus + group mean (rows of one o live in this wave) --
    const float bo = bias[o_g];
#pragma unroll
    for (int nt = 0; nt < NT_W; nt++) {
        float s = 0.f;
#pragma unroll
        for (int mt = 0; mt < MT_W; mt++)
#pragma unroll
            for (int r = 0; r < 4; r++)
                s += softplus_f(acc[mt][nt][r] + bo);
        s += __shfl_xor(s, 16);
        s += __shfl_xor(s, 32);
        if (quad == 0)
            out[((size_t)b * NCTOT + o_g) * SITES + s0 + (wave_nt0 + nt) * 16 + m16]
                = s * (1.f / 48.f);
    }
}

// ---------------------------------------------------------------------------
// Reduce stage A: per (b, s-chunk) block -> 3 partial sums
// ---------------------------------------------------------------------------
__global__ __launch_bounds__(256) void reduce_a(
    const float* __restrict__ A2, const int* __restrict__ NN,
    const int* __restrict__ s2sh, const float* __restrict__ sw,
    const float* __restrict__ Avc, float* __restrict__ partial)
{
    const int b = blockIdx.x >> 4;
    const int chunk = blockIdx.x & 15;
    const int tid = threadIdx.x;
    const int s = (chunk << 8) + tid;
    const float* a = A2 + (size_t)b * SITES;

    float y0 = 0.f, y1 = 0.f, y2 = 0.f;
#pragma unroll
    for (int n = 0; n < NGB; n++) {
        float v = a[NN[n * SITES + s]];
        y0 = fmaf(Avc[n],           v, y0);
        y1 = fmaf(Avc[NGB + n],     v, y1);
        y2 = fmaf(Avc[2 * NGB + n], v, y2);
    }
    const float wgt = sw[s2sh[s]];
    y0 *= wgt; y1 *= wgt; y2 *= wgt;

    __shared__ float red[3][256];
    red[0][tid] = y0; red[1][tid] = y1; red[2][tid] = y2;
    __syncthreads();
    for (int st = 128; st > 0; st >>= 1) {
        if (tid < st) {
            red[0][tid] += red[0][tid + st];
            red[1][tid] += red[1][tid + st];
            red[2][tid] += red[2][tid + st];
        }
        __syncthreads();
    }
    if (tid < 3) partial[(b * 16 + chunk) * 3 + tid] = red[tid][0];
}

__global__ __launch_bounds__(256) void reduce_b(
    const float* __restrict__ partial, float* __restrict__ out)
{
    int t = threadIdx.x;
    if (t < BATCH * 3) {
        int b = t / 3, d = t - b * 3;
        float s = 0.f;
        for (int c = 0; c < 16; c++) s += partial[(b * 16 + c) * 3 + d];
        out[t] = s * (1.f / (float)SITES);
    }
}

// ---------------------------------------------------------------------------
extern "C" void kernel_launch(void* const* d_in, const int* in_sizes, int n_in,
                              void* d_out, int out_size, void* d_ws, size_t ws_size,
                              hipStream_t stream)
{
    const float* InStates = (const float*)d_in[0];
    const float* Psi0     = (const float*)d_in[1];
    const float* bias0    = (const float*)d_in[2];
    const float* Psi1     = (const float*)d_in[3];
    const float* bias1    = (const float*)d_in[4];
    const float* Psi2     = (const float*)d_in[5];
    const float* bias2    = (const float*)d_in[6];
    const float* wtVC     = (const float*)d_in[7];
    const float* ShellW   = (const float*)d_in[8];
    const float* gdiags   = (const float*)d_in[9];
    const int*   GnnPerms = (const int*)d_in[10];
    const int*   NNSites  = (const int*)d_in[11];
    const int*   S2Sh     = (const int*)d_in[12];

    float*  ws   = (float*)d_ws;
    float*  Avc  = ws + OFF_AVC;
    __bf16* U    = (__bf16*)(ws + OFF_U);
    float*  A0   = ws + OFF_A0;
    float*  A1   = ws + OFF_A1;
    float*  A2   = ws + OFF_A0;      // alias: A0 dead once L2 runs
    float*  PART = ws + OFF_PART;

    float* out = (float*)d_out;      // (64,3) f32

    hipMemsetAsync(Avc, 0, 39 * sizeof(float), stream);
    precompute_kernel<<<272, 256, 0, stream>>>(Psi0, Psi1, Psi2, wtVC, gdiags,
                                               GnnPerms, ws);

    // L0: K=13 pad 32, M=192 (4 o x 48), 2 o-blocks, CT=64
    layer_mfma<1, 8, 4, 64, 32, 1>
        <<<BATCH * (SITES / 64) * 2, 256, 0, stream>>>(
            InStates, U + UW0H, U + UW0L, bias0, NNSites, A0);
    // L1: K=104 pad 128, M=192, 2 o-blocks, CT=64
    layer_mfma<8, 8, 4, 64, 128, 1>
        <<<BATCH * (SITES / 64) * 2, 256, 0, stream>>>(
            A0, U + UW1H, U + UW1L, bias1, NNSites, A1);
    // L2: K=104 pad 128, M=48 (1 o), waves split cols (NWN=4), CT=64
    layer_mfma<8, 1, 1, 64, 128, 4>
        <<<BATCH * (SITES / 64), 256, 0, stream>>>(
            A1, U + UW2H, U + UW2L, bias2, NNSites, A2);

    reduce_a<<<BATCH * 16, 256, 0, stream>>>(A2, NNSites, S2Sh, ShellW, Avc, PART);
    reduce_b<<<1, 256, 0, stream>>>(PART, out);
}

// Round 8
// 387.012 us; speedup vs baseline: 2.9660x; 1.5612x over previous
//
#include <hip/hip_runtime.h>
#include <hip/hip_bf16.h>

// Problem constants (SymNetDP): B=64, S=4096, NGB=13, NG=48, DIM=3, NCH={8,8,1}
#define BATCH 64
#define SITES 4096
#define NGB 13
#define NGRP 48
#define SDIM 3

typedef __bf16 bf16x8 __attribute__((ext_vector_type(8)));
typedef __bf16 bf16x4 __attribute__((ext_vector_type(4)));
typedef float  f32x4  __attribute__((ext_vector_type(4)));

// ---------------------------------------------------------------------------
// Workspace layout:
//   Avc  : 39 f32 (pad 64)                      @ float 0
//   U    : bf16 region, 135168 elems            @ float 64
//     W0H [384][32] 12288 | W0L @12288 | W1H [384][128] @24576 (49152) |
//     W1L @73728 | W2H [48][128] @122880 (6144) | W2L @129024
//   A0   : (B,S,8) channel-last, 2097152 f32    @ float 67648  (A2 aliases)
//   A1   : (B,S,8) channel-last, 2097152 f32    @ float 2164800
//   PART : (64,16,3) 3072                       @ float 4261952
// ---------------------------------------------------------------------------
#define OFF_AVC  0
#define OFF_U    64
#define OFF_A0   67648
#define OFF_A1   2164800
#define OFF_PART 4261952
#define UW0H 0
#define UW0L 12288
#define UW1H 24576
#define UW1L 73728
#define UW2H 122880
#define UW2L 129024

__device__ __forceinline__ float softplus_f(float h) {
    return fmaxf(h, 0.f) + __logf(1.f + __expf(-fabsf(h)));
}

// ---------------------------------------------------------------------------
// Precompute: rotated weights, bf16 hi/lo split, [row=o*48+g][KPAD] row-major
// (zero-padded K); plus Avc (atomics, zeroed by memset).
// ---------------------------------------------------------------------------
__global__ __launch_bounds__(256) void precompute_kernel(
    const float* __restrict__ Psi0, const float* __restrict__ Psi1,
    const float* __restrict__ Psi2, const float* __restrict__ wtVC,
    const float* __restrict__ gdiags, const int* __restrict__ perms,
    float* __restrict__ ws)
{
    float*  Avc = ws + OFF_AVC;
    __bf16* U   = (__bf16*)(ws + OFF_U);
    int t = blockIdx.x * 256 + threadIdx.x;
    if (t < 12288) {                       // W0: [384][32]
        int k = t & 31, row = t >> 5;
        int o = row / NGRP, g = row - o * NGRP;
        float w = (k < NGB) ? Psi0[o * NGB + perms[g * NGB + k]] : 0.f;
        __bf16 hi = (__bf16)w;
        U[UW0H + t] = hi;
        U[UW0L + t] = (__bf16)(w - (float)hi);
    } else if (t < 61440) {                // W1: [384][128]
        int u = t - 12288;
        int k = u & 127, row = u >> 7;
        int o = row / NGRP, g = row - o * NGRP;
        float w = 0.f;
        if (k < 104) { int c = k / NGB, j = k - c * NGB;
                       w = Psi1[(o * 8 + c) * NGB + perms[g * NGB + j]]; }
        __bf16 hi = (__bf16)w;
        U[UW1H + u] = hi;
        U[UW1L + u] = (__bf16)(w - (float)hi);
    } else if (t < 67584) {                // W2: [48][128]
        int u = t - 61440;
        int k = u & 127, g = u >> 7;
        float w = 0.f;
        if (k < 104) { int c = k / NGB, j = k - c * NGB;
                       w = Psi2[c * NGB + perms[g * NGB + j]]; }
        __bf16 hi = (__bf16)w;
        U[UW2H + u] = hi;
        U[UW2L + u] = (__bf16)(w - (float)hi);
    } else if (t < 67584 + 39 * NGRP) {    // Avc
        int t2 = t - 67584;
        int g = t2 % NGRP, u = t2 / NGRP;
        int d = u / NGB, n = u % NGB;
        const int row = g * SDIM + d;
        float s = 0.f;
        for (int k = 0; k < NGRP * SDIM; k++) {
            int g2 = k / SDIM, d2 = k - g2 * SDIM;
            float p = wtVC[d2 * NGB + perms[g2 * NGB + n]];
            s = fmaf(gdiags[row * (NGRP * SDIM) + k], p, s);
        }
        atomicAdd(&Avc[u], s * (1.f / 48.f));
    }
}

// ---------------------------------------------------------------------------
// MFMA gconv layer (bf16x3 split), v8.
// 512 threads = 8 waves; block covers ALL output channels x CT cols.
// prev is channel-last (B,S,NCIN) for NCIN=8 -> gather is 2x float4 per site.
// LDS: xh/xl [col][KSTR], KSTR=KPAD+4 halfwords (264B rows): b16 staging
// writes 2-way (free), B-frags via 2x ds_read_b64 (8B-aligned, conflict-free).
// Wave owns one o (L0/L1) or one col-16 (L2). One barrier total.
// A-frags (weights hi/lo) read per-lane from global (L2-resident).
// D layout: row=quad*4+r, col=lane&15; epilogue softplus + shfl group-mean.
// ---------------------------------------------------------------------------
template<int NCIN, int NCTOT, int CT, int KPAD, int NWN>
__global__ __launch_bounds__(512) void layer_mfma(
    const float* __restrict__ prev,   // (B,S) if NCIN==1 else (B,S,8)
    const __bf16* __restrict__ Wh,    // [NCTOT*48][KPAD]
    const __bf16* __restrict__ Wl,
    const float* __restrict__ bias,   // (NCTOT,)
    const int*   __restrict__ NN,     // (13, S)
    float* __restrict__ out)          // (B,S,NCTOT) channel-last
{
    constexpr int K      = NCIN * NGB;
    constexpr int M      = NCTOT * NGRP;
    constexpr int MTILES = M / 16, NTILES = CT / 16;
    constexpr int NWM    = 8 / NWN;
    constexpr int MT_W   = MTILES / NWM, NT_W = NTILES / NWN;
    constexpr int KT     = KPAD / 32;
    constexpr int KSTR   = KPAD + 4;   // halfwords; word-stride ≡2 mod 4

    static_assert(MT_W * 16 == NGRP, "wave covers exactly one o");
    static_assert(NWM * MT_W == MTILES && NWN * NT_W == NTILES, "");
    static_assert((KPAD & 31) == 0, "");

    __shared__ __bf16 xh_lds[CT * KSTR];
    __shared__ __bf16 xl_lds[CT * KSTR];

    const int tid  = threadIdx.x;
    const int wave = tid >> 6, lane = tid & 63;
    const int m16  = lane & 15, quad = lane >> 4;

    const int b  = blockIdx.x / (SITES / CT);
    const int s0 = (blockIdx.x % (SITES / CT)) * CT;

    // --- gather + split X straight into LDS (no nn_lds, no extra barrier) ---
    for (int site = tid; site < NGB * CT; site += 512) {
        int j = site / CT, col = site % CT;      // CT pow2 -> shifts
        int nn = NN[j * SITES + s0 + col];
        if constexpr (NCIN == 1) {
            float v = prev[(size_t)b * SITES + nn];
            __bf16 hi = (__bf16)v;
            xh_lds[col * KSTR + j] = hi;
            xl_lds[col * KSTR + j] = (__bf16)(v - (float)hi);
        } else {
            const float4* p4 = (const float4*)(prev + ((size_t)(b * SITES + nn)) * 8);
            float4 u0 = p4[0], u1 = p4[1];
            float v[8] = {u0.x, u0.y, u0.z, u0.w, u1.x, u1.y, u1.z, u1.w};
#pragma unroll
            for (int c = 0; c < 8; c++) {
                int k = c * NGB + j;
                __bf16 hi = (__bf16)v[c];
                xh_lds[col * KSTR + k] = hi;
                xl_lds[col * KSTR + k] = (__bf16)(v[c] - (float)hi);
            }
        }
    }
    // zero-pad k in [K, KPAD)
    for (int e = tid; e < CT * (KPAD - K); e += 512) {
        int col = e / (KPAD - K), p = e - col * (KPAD - K);
        xh_lds[col * KSTR + K + p] = (__bf16)0.f;
        xl_lds[col * KSTR + K + p] = (__bf16)0.f;
    }
    __syncthreads();

    const int wave_mt0 = (wave / NWN) * MT_W;
    const int wave_nt0 = (wave % NWN) * NT_W;
    const int o_g      = (wave_mt0 * 16) / NGRP;

    f32x4 acc[MT_W][NT_W];
#pragma unroll
    for (int mt = 0; mt < MT_W; mt++)
#pragma unroll
        for (int nt = 0; nt < NT_W; nt++) acc[mt][nt] = (f32x4){0.f, 0.f, 0.f, 0.f};

    // --- K loop: hi*hi + lo*hi + hi*lo per (tile, k32) ----------------------
#pragma unroll 1
    for (int kt = 0; kt < KT; kt++) {
        const int koff = kt * 32 + quad * 8;
        bf16x8 ah[MT_W], al[MT_W];
#pragma unroll
        for (int mt = 0; mt < MT_W; mt++) {
            int row = (wave_mt0 + mt) * 16 + m16;
            ah[mt] = *(const bf16x8*)(Wh + (size_t)row * KPAD + koff);
            al[mt] = *(const bf16x8*)(Wl + (size_t)row * KPAD + koff);
        }
#pragma unroll
        for (int nt = 0; nt < NT_W; nt++) {
            int cbase = ((wave_nt0 + nt) * 16 + m16) * KSTR + koff;
            bf16x4 h0 = *(const bf16x4*)(xh_lds + cbase);
            bf16x4 h1 = *(const bf16x4*)(xh_lds + cbase + 4);
            bf16x4 l0 = *(const bf16x4*)(xl_lds + cbase);
            bf16x4 l1 = *(const bf16x4*)(xl_lds + cbase + 4);
            bf16x8 bh = __builtin_shufflevector(h0, h1, 0, 1, 2, 3, 4, 5, 6, 7);
            bf16x8 bl = __builtin_shufflevector(l0, l1, 0, 1, 2, 3, 4, 5, 6, 7);
#pragma unroll
            for (int mt = 0; mt < MT_W; mt++) {
                acc[mt][nt] = __builtin_amdgcn_mfma_f32_16x16x32_bf16(
                    ah[mt], bh, acc[mt][nt], 0, 0, 0);
                acc[mt][nt] = __builtin_amdgcn_mfma_f32_16x16x32_bf16(
                    al[mt], bh, acc[mt][nt], 0, 0, 0);
                acc[mt][nt] = __builtin_amdgcn_mfma_f32_16x16x32_bf16(
                    ah[mt], bl, acc[mt][nt], 0, 0, 0);
            }
        }
    }

    // --- epilogue: softplus + group mean (one o per wave) -------------------
    const float bo = bias[o_g];
#pragma unroll
    for (int nt = 0; nt < NT_W; nt++) {
        float s = 0.f;
#pragma unroll
        for (int mt = 0; mt < MT_W; mt++)
#pragma unroll
            for (int r = 0; r < 4; r++)
                s += softplus_f(acc[mt][nt][r] + bo);
        s += __shfl_xor(s, 16);
        s += __shfl_xor(s, 32);
        if (quad == 0)
            out[((size_t)(b * SITES + s0 + (wave_nt0 + nt) * 16 + m16)) * NCTOT + o_g]
                = s * (1.f / 48.f);
    }
}

// ---------------------------------------------------------------------------
// Reduce stage A: per (b, s-chunk) block -> 3 partial sums
// ---------------------------------------------------------------------------
__global__ __launch_bounds__(256) void reduce_a(
    const float* __restrict__ A2, const int* __restrict__ NN,
    const int* __restrict__ s2sh, const float* __restrict__ sw,
    const float* __restrict__ Avc, float* __restrict__ partial)
{
    const int b = blockIdx.x >> 4;
    const int chunk = blockIdx.x & 15;
    const int tid = threadIdx.x;
    const int s = (chunk << 8) + tid;
    const float* a = A2 + (size_t)b * SITES;

    float y0 = 0.f, y1 = 0.f, y2 = 0.f;
#pragma unroll
    for (int n = 0; n < NGB; n++) {
        float v = a[NN[n * SITES + s]];
        y0 = fmaf(Avc[n],           v, y0);
        y1 = fmaf(Avc[NGB + n],     v, y1);
        y2 = fmaf(Avc[2 * NGB + n], v, y2);
    }
    const float wgt = sw[s2sh[s]];
    y0 *= wgt; y1 *= wgt; y2 *= wgt;

    __shared__ float red[3][256];
    red[0][tid] = y0; red[1][tid] = y1; red[2][tid] = y2;
    __syncthreads();
    for (int st = 128; st > 0; st >>= 1) {
        if (tid < st) {
            red[0][tid] += red[0][tid + st];
            red[1][tid] += red[1][tid + st];
            red[2][tid] += red[2][tid + st];
        }
        __syncthreads();
    }
    if (tid < 3) partial[(b * 16 + chunk) * 3 + tid] = red[tid][0];
}

__global__ __launch_bounds__(256) void reduce_b(
    const float* __restrict__ partial, float* __restrict__ out)
{
    int t = threadIdx.x;
    if (t < BATCH * 3) {
        int b = t / 3, d = t - b * 3;
        float s = 0.f;
        for (int c = 0; c < 16; c++) s += partial[(b * 16 + c) * 3 + d];
        out[t] = s * (1.f / (float)SITES);
    }
}

// ---------------------------------------------------------------------------
extern "C" void kernel_launch(void* const* d_in, const int* in_sizes, int n_in,
                              void* d_out, int out_size, void* d_ws, size_t ws_size,
                              hipStream_t stream)
{
    const float* InStates = (const float*)d_in[0];
    const float* Psi0     = (const float*)d_in[1];
    const float* bias0    = (const float*)d_in[2];
    const float* Psi1     = (const float*)d_in[3];
    const float* bias1    = (const float*)d_in[4];
    const float* Psi2     = (const float*)d_in[5];
    const float* bias2    = (const float*)d_in[6];
    const float* wtVC     = (const float*)d_in[7];
    const float* ShellW   = (const float*)d_in[8];
    const float* gdiags   = (const float*)d_in[9];
    const int*   GnnPerms = (const int*)d_in[10];
    const int*   NNSites  = (const int*)d_in[11];
    const int*   S2Sh     = (const int*)d_in[12];

    float*  ws   = (float*)d_ws;
    float*  Avc  = ws + OFF_AVC;
    __bf16* U    = (__bf16*)(ws + OFF_U);
    float*  A0   = ws + OFF_A0;      // (B,S,8) channel-last
    float*  A1   = ws + OFF_A1;      // (B,S,8) channel-last
    float*  A2   = ws + OFF_A0;      // (B,S) alias: A0 dead once L2 runs
    float*  PART = ws + OFF_PART;

    float* out = (float*)d_out;      // (64,3) f32

    hipMemsetAsync(Avc, 0, 39 * sizeof(float), stream);
    precompute_kernel<<<272, 256, 0, stream>>>(Psi0, Psi1, Psi2, wtVC, gdiags,
                                               GnnPerms, ws);

    // L0: K=13 pad 32, M=384 (8 o), CT=64, wave=o
    layer_mfma<1, 8, 64, 32, 1><<<BATCH * (SITES / 64), 512, 0, stream>>>(
        InStates, U + UW0H, U + UW0L, bias0, NNSites, A0);
    // L1: K=104 pad 128, M=384, CT=64, wave=o
    layer_mfma<8, 8, 64, 128, 1><<<BATCH * (SITES / 64), 512, 0, stream>>>(
        A0, U + UW1H, U + UW1L, bias1, NNSites, A1);
    // L2: K=104 pad 128, M=48 (1 o), CT=128, waves split cols
    layer_mfma<8, 1, 128, 128, 8><<<BATCH * (SITES / 128), 512, 0, stream>>>(
        A1, U + UW2H, U + UW2L, bias2, NNSites, A2);

    reduce_a<<<BATCH * 16, 256, 0, stream>>>(A2, NNSites, S2Sh, ShellW, Avc, PART);
    reduce_b<<<1, 256, 0, stream>>>(PART, out);
}

// Round 9
// 376.657 us; speedup vs baseline: 3.0476x; 1.0275x over previous
//
#include <hip/hip_runtime.h>
#include <hip/hip_bf16.h>

// Problem constants (SymNetDP): B=64, S=4096, NGB=13, NG=48, DIM=3, NCH={8,8,1}
#define BATCH 64
#define SITES 4096
#define NGB 13
#define NGRP 48
#define SDIM 3

typedef __bf16 bf16x8 __attribute__((ext_vector_type(8)));
typedef float  f32x4  __attribute__((ext_vector_type(4)));

// ---------------------------------------------------------------------------
// Workspace layout:
//   Avc  : 39 f32 (pad 64)                      @ float 0
//   U    : bf16 region, 135168 elems            @ float 64
//     W0H [384][32] 12288 | W0L @12288 | W1H [384][128] @24576 (49152) |
//     W1L @73728 | W2H [48][128] @122880 (6144) | W2L @129024
//   A0   : (B,S,8) channel-last, 2097152 f32    @ float 67648  (A2 aliases)
//   A1   : (B,S,8) channel-last, 2097152 f32    @ float 2164800
//   PART : (64,16,3) 3072                       @ float 4261952
// K-packing for NCIN=8 layers: k = j*8 + c  (site's 8 channels contiguous).
// ---------------------------------------------------------------------------
#define OFF_AVC  0
#define OFF_U    64
#define OFF_A0   67648
#define OFF_A1   2164800
#define OFF_PART 4261952
#define UW0H 0
#define UW0L 12288
#define UW1H 24576
#define UW1L 73728
#define UW2H 122880
#define UW2L 129024

__device__ __forceinline__ float softplus_f(float h) {
    return fmaxf(h, 0.f) + __logf(1.f + __expf(-fabsf(h)));
}

// ---------------------------------------------------------------------------
// Precompute: rotated weights, bf16 hi/lo split, [row=o*48+g][KPAD] with
// k = j*8+c packing for K=104 layers (k = j for layer 0); plus Avc.
// ---------------------------------------------------------------------------
__global__ __launch_bounds__(256) void precompute_kernel(
    const float* __restrict__ Psi0, const float* __restrict__ Psi1,
    const float* __restrict__ Psi2, const float* __restrict__ wtVC,
    const float* __restrict__ gdiags, const int* __restrict__ perms,
    float* __restrict__ ws)
{
    float*  Avc = ws + OFF_AVC;
    __bf16* U   = (__bf16*)(ws + OFF_U);
    int t = blockIdx.x * 256 + threadIdx.x;
    if (t < 12288) {                       // W0: [384][32], k=j
        int k = t & 31, row = t >> 5;
        int o = row / NGRP, g = row - o * NGRP;
        float w = (k < NGB) ? Psi0[o * NGB + perms[g * NGB + k]] : 0.f;
        __bf16 hi = (__bf16)w;
        U[UW0H + t] = hi;
        U[UW0L + t] = (__bf16)(w - (float)hi);
    } else if (t < 61440) {                // W1: [384][128], k=j*8+c
        int u = t - 12288;
        int k = u & 127, row = u >> 7;
        int o = row / NGRP, g = row - o * NGRP;
        float w = 0.f;
        if (k < 104) { int j = k >> 3, c = k & 7;
                       w = Psi1[(o * 8 + c) * NGB + perms[g * NGB + j]]; }
        __bf16 hi = (__bf16)w;
        U[UW1H + u] = hi;
        U[UW1L + u] = (__bf16)(w - (float)hi);
    } else if (t < 67584) {                // W2: [48][128], k=j*8+c
        int u = t - 61440;
        int k = u & 127, g = u >> 7;
        float w = 0.f;
        if (k < 104) { int j = k >> 3, c = k & 7;
                       w = Psi2[c * NGB + perms[g * NGB + j]]; }
        __bf16 hi = (__bf16)w;
        U[UW2H + u] = hi;
        U[UW2L + u] = (__bf16)(w - (float)hi);
    } else if (t < 67584 + 39 * NGRP) {    // Avc
        int t2 = t - 67584;
        int g = t2 % NGRP, u = t2 / NGRP;
        int d = u / NGB, n = u % NGB;
        const int row = g * SDIM + d;
        float s = 0.f;
        for (int k = 0; k < NGRP * SDIM; k++) {
            int g2 = k / SDIM, d2 = k - g2 * SDIM;
            float p = wtVC[d2 * NGB + perms[g2 * NGB + n]];
            s = fmaf(gdiags[row * (NGRP * SDIM) + k], p, s);
        }
        atomicAdd(&Avc[u], s * (1.f / 48.f));
    }
}

// ---------------------------------------------------------------------------
// MFMA gconv layer (bf16x3 split), v9.
// k = j*8+c packing -> staging writes ONE bf16x8 (b128) per site per array.
// KSTR halfwords chosen 16B-aligned with word-stride ≡ 4 mod 32 -> col-major
// b128 LDS ops are 2-way only (free). B-frags: single ds_read_b128.
// kt-loop fully unrolled -> all A-frag (weight) global loads issue up front.
// Wave owns one o (rows) and NT_W col-tiles; epilogue softplus + shfl mean.
// ---------------------------------------------------------------------------
template<int NCIN, int NCTOT, int CT, int KPAD, int KSTR, int NWAVES, int NWN>
__global__ __launch_bounds__(NWAVES * 64) void layer_mfma(
    const float* __restrict__ prev,   // (B,S) if NCIN==1 else (B,S,8)
    const __bf16* __restrict__ Wh,    // [NCTOT*48][KPAD]
    const __bf16* __restrict__ Wl,
    const float* __restrict__ bias,   // (NCTOT,)
    const int*   __restrict__ NN,     // (13, S)
    float* __restrict__ out)          // (B,S,NCTOT) channel-last
{
    constexpr int NTHR   = NWAVES * 64;
    constexpr int K      = NCIN * NGB;
    constexpr int M      = NCTOT * NGRP;
    constexpr int MTILES = M / 16, NTILES = CT / 16;
    constexpr int NWM    = NWAVES / NWN;
    constexpr int MT_W   = MTILES / NWM, NT_W = NTILES / NWN;
    constexpr int KT     = KPAD / 32;

    static_assert(MT_W * 16 == NGRP, "wave covers exactly one o");
    static_assert(NWM * MT_W == MTILES && NWN * NT_W == NTILES, "");
    static_assert((KPAD & 31) == 0 && (KSTR & 7) == 0, "");

    __shared__ __bf16 xh_lds[CT * KSTR];
    __shared__ __bf16 xl_lds[CT * KSTR];

    const int tid  = threadIdx.x;
    const int wave = tid >> 6, lane = tid & 63;
    const int m16  = lane & 15, quad = lane >> 4;

    const int b  = blockIdx.x / (SITES / CT);
    const int s0 = (blockIdx.x % (SITES / CT)) * CT;

    // --- gather + split X into LDS ------------------------------------------
    if constexpr (NCIN == 1) {
        for (int site = tid; site < NGB * CT; site += NTHR) {
            int j = site / CT, col = site % CT;
            int nn = NN[j * SITES + s0 + col];
            float v = prev[(size_t)b * SITES + nn];
            __bf16 hi = (__bf16)v;
            xh_lds[col * KSTR + j] = hi;
            xl_lds[col * KSTR + j] = (__bf16)(v - (float)hi);
        }
        for (int e = tid; e < CT * (KPAD - NGB); e += NTHR) {
            int col = e / (KPAD - NGB), p = e % (KPAD - NGB);
            xh_lds[col * KSTR + NGB + p] = (__bf16)0.f;
            xl_lds[col * KSTR + NGB + p] = (__bf16)0.f;
        }
    } else {
        for (int site = tid; site < NGB * CT; site += NTHR) {
            int j = site / CT, col = site % CT;
            int nn = NN[j * SITES + s0 + col];
            const float4* p4 = (const float4*)(prev + ((size_t)(b * SITES + nn)) * 8);
            float4 u0 = p4[0], u1 = p4[1];
            float v[8] = {u0.x, u0.y, u0.z, u0.w, u1.x, u1.y, u1.z, u1.w};
            bf16x8 hv, lv;
#pragma unroll
            for (int c = 0; c < 8; c++) {
                __bf16 hi = (__bf16)v[c];
                hv[c] = hi;
                lv[c] = (__bf16)(v[c] - (float)hi);
            }
            *(bf16x8*)(xh_lds + col * KSTR + j * 8) = hv;
            *(bf16x8*)(xl_lds + col * KSTR + j * 8) = lv;
        }
        // zero-pad k in [104, 128): 3 x b128 per column
        const bf16x8 z8 = {};
        for (int e = tid; e < CT * 3; e += NTHR) {
            int col = e % CT, z = e / CT;
            *(bf16x8*)(xh_lds + col * KSTR + 104 + z * 8) = z8;
            *(bf16x8*)(xl_lds + col * KSTR + 104 + z * 8) = z8;
        }
    }
    __syncthreads();

    const int wave_mt0 = (wave / NWN) * MT_W;
    const int wave_nt0 = (wave % NWN) * NT_W;
    const int o_g      = (wave_mt0 * 16) / NGRP;

    f32x4 acc[MT_W][NT_W];
#pragma unroll
    for (int mt = 0; mt < MT_W; mt++)
#pragma unroll
        for (int nt = 0; nt < NT_W; nt++) acc[mt][nt] = (f32x4){0.f, 0.f, 0.f, 0.f};

    // --- K loop (FULL unroll: A-frag loads hoisted/overlapped) --------------
#pragma unroll
    for (int kt = 0; kt < KT; kt++) {
        const int koff = kt * 32 + quad * 8;
        bf16x8 ah[MT_W], al[MT_W], bh[NT_W], bl[NT_W];
#pragma unroll
        for (int mt = 0; mt < MT_W; mt++) {
            int row = (wave_mt0 + mt) * 16 + m16;
            ah[mt] = *(const bf16x8*)(Wh + (size_t)row * KPAD + koff);
            al[mt] = *(const bf16x8*)(Wl + (size_t)row * KPAD + koff);
        }
#pragma unroll
        for (int nt = 0; nt < NT_W; nt++) {
            int cbase = ((wave_nt0 + nt) * 16 + m16) * KSTR + koff;
            bh[nt] = *(const bf16x8*)(xh_lds + cbase);
            bl[nt] = *(const bf16x8*)(xl_lds + cbase);
        }
#pragma unroll
        for (int mt = 0; mt < MT_W; mt++)
#pragma unroll
            for (int nt = 0; nt < NT_W; nt++) {
                acc[mt][nt] = __builtin_amdgcn_mfma_f32_16x16x32_bf16(
                    ah[mt], bh[nt], acc[mt][nt], 0, 0, 0);
                acc[mt][nt] = __builtin_amdgcn_mfma_f32_16x16x32_bf16(
                    al[mt], bh[nt], acc[mt][nt], 0, 0, 0);
                acc[mt][nt] = __builtin_amdgcn_mfma_f32_16x16x32_bf16(
                    ah[mt], bl[nt], acc[mt][nt], 0, 0, 0);
            }
    }

    // --- epilogue: softplus + group mean (one o per wave) -------------------
    const float bo = bias[o_g];
#pragma unroll
    for (int nt = 0; nt < NT_W; nt++) {
        float s = 0.f;
#pragma unroll
        for (int mt = 0; mt < MT_W; mt++)
#pragma unroll
            for (int r = 0; r < 4; r++)
                s += softplus_f(acc[mt][nt][r] + bo);
        s += __shfl_xor(s, 16);
        s += __shfl_xor(s, 32);
        if (quad == 0)
            out[((size_t)(b * SITES + s0 + (wave_nt0 + nt) * 16 + m16)) * NCTOT + o_g]
                = s * (1.f / 48.f);
    }
}

// ---------------------------------------------------------------------------
// Reduce stage A: per (b, s-chunk) block -> 3 partial sums
// ---------------------------------------------------------------------------
__global__ __launch_bounds__(256) void reduce_a(
    const float* __restrict__ A2, const int* __restrict__ NN,
    const int* __restrict__ s2sh, const float* __restrict__ sw,
    const float* __restrict__ Avc, float* __restrict__ partial)
{
    const int b = blockIdx.x >> 4;
    const int chunk = blockIdx.x & 15;
    const int tid = threadIdx.x;
    const int s = (chunk << 8) + tid;
    const float* a = A2 + (size_t)b * SITES;

    float y0 = 0.f, y1 = 0.f, y2 = 0.f;
#pragma unroll
    for (int n = 0; n < NGB; n++) {
        float v = a[NN[n * SITES + s]];
        y0 = fmaf(Avc[n],           v, y0);
        y1 = fmaf(Avc[NGB + n],     v, y1);
        y2 = fmaf(Avc[2 * NGB + n], v, y2);
    }
    const float wgt = sw[s2sh[s]];
    y0 *= wgt; y1 *= wgt; y2 *= wgt;

    __shared__ float red[3][256];
    red[0][tid] = y0; red[1][tid] = y1; red[2][tid] = y2;
    __syncthreads();
    for (int st = 128; st > 0; st >>= 1) {
        if (tid < st) {
            red[0][tid] += red[0][tid + st];
            red[1][tid] += red[1][tid + st];
            red[2][tid] += red[2][tid + st];
        }
        __syncthreads();
    }
    if (tid < 3) partial[(b * 16 + chunk) * 3 + tid] = red[tid][0];
}

__global__ __launch_bounds__(256) void reduce_b(
    const float* __restrict__ partial, float* __restrict__ out)
{
    int t = threadIdx.x;
    if (t < BATCH * 3) {
        int b = t / 3, d = t - b * 3;
        float s = 0.f;
        for (int c = 0; c < 16; c++) s += partial[(b * 16 + c) * 3 + d];
        out[t] = s * (1.f / (float)SITES);
    }
}

// ---------------------------------------------------------------------------
extern "C" void kernel_launch(void* const* d_in, const int* in_sizes, int n_in,
                              void* d_out, int out_size, void* d_ws, size_t ws_size,
                              hipStream_t stream)
{
    const float* InStates = (const float*)d_in[0];
    const float* Psi0     = (const float*)d_in[1];
    const float* bias0    = (const float*)d_in[2];
    const float* Psi1     = (const float*)d_in[3];
    const float* bias1    = (const float*)d_in[4];
    const float* Psi2     = (const float*)d_in[5];
    const float* bias2    = (const float*)d_in[6];
    const float* wtVC     = (const float*)d_in[7];
    const float* ShellW   = (const float*)d_in[8];
    const float* gdiags   = (const float*)d_in[9];
    const int*   GnnPerms = (const int*)d_in[10];
    const int*   NNSites  = (const int*)d_in[11];
    const int*   S2Sh     = (const int*)d_in[12];

    float*  ws   = (float*)d_ws;
    float*  Avc  = ws + OFF_AVC;
    __bf16* U    = (__bf16*)(ws + OFF_U);
    float*  A0   = ws + OFF_A0;      // (B,S,8) channel-last
    float*  A1   = ws + OFF_A1;      // (B,S,8) channel-last
    float*  A2   = ws + OFF_A0;      // (B,S) alias: A0 dead once L2 runs
    float*  PART = ws + OFF_PART;

    float* out = (float*)d_out;      // (64,3) f32

    hipMemsetAsync(Avc, 0, 39 * sizeof(float), stream);
    precompute_kernel<<<272, 256, 0, stream>>>(Psi0, Psi1, Psi2, wtVC, gdiags,
                                               GnnPerms, ws);

    // L0: K=13 pad 32, KSTR=40 (80B rows, stride 20 words -> 2-way free)
    layer_mfma<1, 8, 64, 32, 40, 8, 1><<<BATCH * (SITES / 64), 512, 0, stream>>>(
        InStates, U + UW0H, U + UW0L, bias0, NNSites, A0);
    // L1: K=104 pad 128, KSTR=136 (272B rows, stride 68 words -> 2-way free)
    layer_mfma<8, 8, 64, 128, 136, 8, 1><<<BATCH * (SITES / 64), 512, 0, stream>>>(
        A0, U + UW1H, U + UW1L, bias1, NNSites, A1);
    // L2: K=104 pad 128, M=48 (1 o), 4 waves split cols
    layer_mfma<8, 1, 64, 128, 136, 4, 4><<<BATCH * (SITES / 64), 256, 0, stream>>>(
        A1, U + UW2H, U + UW2L, bias2, NNSites, A2);

    reduce_a<<<BATCH * 16, 256, 0, stream>>>(A2, NNSites, S2Sh, ShellW, Avc, PART);
    reduce_b<<<1, 256, 0, stream>>>(PART, out);
}